// Round 23
// baseline (227.203 us; speedup 1.0000x reference)
//
#include <hip/hip_runtime.h>
#include <hip/hip_bf16.h>
#include <math.h>
#include <stdint.h>

#define NLAT 64
#define NLON 127
#define LMAX 64
#define CCH  64
#define TEMB 128
#define ROW  (NLON * CCH)           // 8128
#define PLANE (LMAX * NLON * CCH)   // 520192
#define NEEDED_WS (1024 + 5ull * PLANE * 4ull)   // 10,404,864 B

typedef float vf4 __attribute__((ext_vector_type(4)));

static __device__ __constant__ double PI_D = 3.14159265358979323846;
#define TWO_PI_127F 0.049473784494768665f

// ---------------------------------------------------------------------------
__global__ void k_band(float band, __hip_bfloat16* __restrict__ out) {
    int n = blockIdx.x, t = blockIdx.y, c = threadIdx.x;
    __hip_bfloat162 v;
    v.x = __float2bfloat16(band);
    v.y = __float2bfloat16(band);
    ((__hip_bfloat162*)out)[((size_t)c * 64 + t) * 127 + n] = v;
}

// ---------------------------------------------------------------------------
// K0: Gauss-Legendre nodes (f64 Newton) + weights, ascending.
// ---------------------------------------------------------------------------
__global__ void k_gauss(double* __restrict__ xg, float* __restrict__ wgf) {
    int i = threadIdx.x;
    if (i >= NLAT) return;
    const int n = 64;
    int k = 63 - i;
    double x = cos(PI_D * ((double)k + 0.75) / ((double)n + 0.5));
    for (int it = 0; it < 8; ++it) {
        double p0 = 1.0, p1 = x;
        for (int kk = 2; kk <= n; ++kk) {
            double p2 = ((2.0 * kk - 1.0) * x * p1 - (kk - 1.0) * p0) * (1.0 / kk);
            p0 = p1; p1 = p2;
        }
        double dpn = n * (x * p1 - p0) / (x * x - 1.0);
        x -= p1 / dpn;
    }
    double p0 = 1.0, p1 = x;
    for (int kk = 2; kk <= n; ++kk) {
        double p2 = ((2.0 * kk - 1.0) * x * p1 - (kk - 1.0) * p0) * (1.0 / kk);
        p0 = p1; p1 = p2;
    }
    double dpn = n * (x * p1 - p0) / (x * x - 1.0);
    xg[i] = x;
    wgf[i] = (float)(2.0 / ((1.0 - x * x) * dpn * dpn));
}

// ---------------------------------------------------------------------------
// K1: Pbar_lm -> Pf[j][l][t], j = 63 +/- m.
// ---------------------------------------------------------------------------
__global__ void k_legendre(const double* __restrict__ xg, float* __restrict__ Pf) {
    int m = blockIdx.x;
    int t = threadIdx.x;
    double x = xg[t];
    double sx = sqrt(fmax(1.0 - x * x, 0.0));
    double pmm = sqrt(1.0 / (4.0 * PI_D));
    for (int k = 1; k <= m; ++k)
        pmm *= -sqrt((2.0 * k + 1.0) / (2.0 * k)) * sx;
    float sgn = (m & 1) ? -1.0f : 1.0f;
    int jp = (63 + m) * 4096;
    int jn = (63 - m) * 4096;
    for (int l = 0; l < m; ++l) {
        Pf[jp + l * 64 + t] = 0.0f;
        if (m) Pf[jn + l * 64 + t] = 0.0f;
    }
    Pf[jp + m * 64 + t] = (float)pmm;
    if (m) Pf[jn + m * 64 + t] = sgn * (float)pmm;
    if (m + 1 < LMAX) {
        double plm2 = pmm;
        double plm1 = sqrt(2.0 * m + 3.0) * x * pmm;
        Pf[jp + (m + 1) * 64 + t] = (float)plm1;
        if (m) Pf[jn + (m + 1) * 64 + t] = sgn * (float)plm1;
        for (int l = m + 2; l < LMAX; ++l) {
            double a = sqrt((4.0 * (double)l * l - 1.0) / ((double)l * l - (double)m * m));
            double lm1 = (double)(l - 1);
            double b = sqrt((lm1 * lm1 - (double)m * m) / (4.0 * lm1 * lm1 - 1.0));
            double pl = a * (x * plm1 - b * plm2);
            Pf[jp + l * 64 + t] = (float)pl;
            if (m) Pf[jn + l * 64 + t] = sgn * (float)pl;
            plm2 = plm1; plm1 = pl;
        }
    }
}

// ---------------------------------------------------------------------------
// K2 (tiled): forward DFT. grid (t=64, jgroup=4), block 256.
// ---------------------------------------------------------------------------
__global__ __launch_bounds__(256) void k_dft_fwd(const float* __restrict__ x,
                                                 float* __restrict__ fmr,
                                                 float* __restrict__ fmi) {
    __shared__ float xs[NLON * CCH];
    __shared__ float ctab[NLON], stab[NLON];
    int t = blockIdx.x;
    int jbase = blockIdx.y * 32;
    int tid = threadIdx.x;
    for (int idx = tid; idx < NLON * CCH; idx += 256)
        xs[idx] = x[t * ROW + idx];
    if (tid < NLON) {
        double th = 2.0 * PI_D * (double)tid / 127.0;
        ctab[tid] = (float)cos(th);
        stab[tid] = (float)sin(th);
    }
    __syncthreads();
    int c = tid & 63;
    int jl = tid >> 6;
    float ar[8], ai[8];
    int p[8], mm[8];
#pragma unroll
    for (int q = 0; q < 8; ++q) {
        ar[q] = 0.f; ai[q] = 0.f; p[q] = 0;
        int j = jbase + jl + 4 * q;
        int m = j - 63;
        mm[q] = (j <= 126) ? (m < 0 ? m + 127 : m) : 0;
    }
    for (int n = 0; n < NLON; ++n) {
        float xv = xs[n * 64 + c];
#pragma unroll
        for (int q = 0; q < 8; ++q) {
            ar[q] = fmaf(xv, ctab[p[q]], ar[q]);
            ai[q] = fmaf(-xv, stab[p[q]], ai[q]);
            p[q] += mm[q]; if (p[q] >= 127) p[q] -= 127;
        }
    }
#pragma unroll
    for (int q = 0; q < 8; ++q) {
        int j = jbase + jl + 4 * q;
        if (j <= 126) {
            fmr[t * ROW + j * 64 + c] = ar[q] * TWO_PI_127F;
            fmi[t * ROW + j * 64 + c] = ai[q] * TWO_PI_127F;
        }
    }
}

// ---------------------------------------------------------------------------
// K3 (tiled): Legendre transform. grid (j=127, lhalf=2), block 256.
// ---------------------------------------------------------------------------
__global__ __launch_bounds__(256) void k_sht(const float* __restrict__ Pf,
                                             const float* __restrict__ wgf,
                                             const float* __restrict__ fmr,
                                             const float* __restrict__ fmi,
                                             float* __restrict__ xsr,
                                             float* __restrict__ xsi) {
    __shared__ float Pw[32 * NLAT];
    __shared__ float fr[NLAT * CCH], fi[NLAT * CCH];
    int j = blockIdx.x;
    int half = blockIdx.y;
    int tid = threadIdx.x;
    for (int idx = tid; idx < 32 * NLAT; idx += 256) {
        int ll = idx >> 6, t = idx & 63;
        Pw[idx] = Pf[j * 4096 + (half * 32 + ll) * 64 + t] * wgf[t];
    }
    for (int idx = tid; idx < NLAT * CCH; idx += 256) {
        int t = idx >> 6;
        fr[idx] = fmr[t * ROW + j * 64 + (idx & 63)];
        fi[idx] = fmi[t * ROW + j * 64 + (idx & 63)];
    }
    __syncthreads();
    int c = tid & 63, lg = tid >> 6;
    float ar[8] = {}, ai[8] = {};
    for (int t = 0; t < NLAT; ++t) {
        float frv = fr[t * 64 + c], fiv = fi[t * 64 + c];
#pragma unroll
        for (int q = 0; q < 8; ++q) {
            float pv = Pw[(lg + 4 * q) * 64 + t];
            ar[q] = fmaf(pv, frv, ar[q]);
            ai[q] = fmaf(pv, fiv, ai[q]);
        }
    }
#pragma unroll
    for (int q = 0; q < 8; ++q) {
        int l = half * 32 + lg + 4 * q;
        xsr[l * ROW + j * 64 + c] = ar[q];
        xsi[l * ROW + j * 64 + c] = ai[q];
    }
}

// ---------------------------------------------------------------------------
// K4 (tiled): per-l complex channel mix. grid (l=64, jq=4), block 256.
// ---------------------------------------------------------------------------
__global__ __launch_bounds__(256) void k_conv(const float* __restrict__ xsr,
                                              const float* __restrict__ xsi,
                                              const float* __restrict__ Wr,
                                              const float* __restrict__ Wi,
                                              float* __restrict__ cvr,
                                              float* __restrict__ cvi) {
    __shared__ float xr[32 * 64], xi[32 * 64];
    __shared__ float wr[64 * 64], wi[64 * 64];
    int l = blockIdx.x;
    int jbase = blockIdx.y * 32;
    int tid = threadIdx.x;
    for (int idx = tid; idx < 2048; idx += 256) {
        int jl = idx >> 6, i = idx & 63;
        int j = jbase + jl;
        bool ok = (j < NLON);
        xr[idx] = ok ? xsr[l * ROW + j * 64 + i] : 0.f;
        xi[idx] = ok ? xsi[l * ROW + j * 64 + i] : 0.f;
    }
    for (int idx = tid; idx < 4096; idx += 256) {
        wr[idx] = Wr[l * 4096 + idx];
        wi[idx] = Wi[l * 4096 + idx];
    }
    __syncthreads();
    int o = tid & 63, jb = tid >> 6;
    float ar[8] = {}, ai[8] = {};
    for (int i = 0; i < 64; ++i) {
        float wrv = wr[i * 64 + o], wiv = wi[i * 64 + o];
#pragma unroll
        for (int q = 0; q < 8; ++q) {
            float xrv = xr[(jb + 4 * q) * 64 + i];
            float xiv = xi[(jb + 4 * q) * 64 + i];
            ar[q] = fmaf(xrv, wrv, fmaf(-xiv, wiv, ar[q]));
            ai[q] = fmaf(xrv, wiv, fmaf(xiv, wrv, ai[q]));
        }
    }
#pragma unroll
    for (int q = 0; q < 8; ++q) {
        int j = jbase + jb + 4 * q;
        if (j < NLON) {
            cvr[l * ROW + j * 64 + o] = ar[q];
            cvi[l * ROW + j * 64 + o] = ai[q];
        }
    }
}

// ---------------------------------------------------------------------------
// K5a/K5b: dense matvec split into TWO single-stream kernels.
// r22: interleaving dwr/dwi (256MB apart) per instruction -> DRAM row thrash
// + shallow per-stream pipelining capped BW at ~3.9 TB/s. One stream per
// kernel: sequential DRAM locality + 8-deep NT pipeline on that stream.
// k ascending per accumulator -> bitwise-identical result.
// ---------------------------------------------------------------------------
__global__ __launch_bounds__(256) void k_dense1(const float* __restrict__ temb,
                                                const float* __restrict__ dw,
                                                const float* __restrict__ cv,
                                                float* __restrict__ rs) {
    __shared__ float te[TEMB];
    int tid = threadIdx.x;
    if (tid < TEMB) te[tid] = temb[tid];
    __syncthreads();
    size_t s4 = (size_t)blockIdx.x * 256 + tid;   // vf4 index, 0..130047
    const vf4* w4 = (const vf4*)dw;
    vf4 acc = {0, 0, 0, 0};
    for (int kk = 0; kk < TEMB; kk += 8) {
        const vf4* p = w4 + (size_t)kk * (PLANE / 4) + s4;
        vf4 a0 = __builtin_nontemporal_load(p);
        vf4 a1 = __builtin_nontemporal_load(p + 1 * (PLANE / 4));
        vf4 a2 = __builtin_nontemporal_load(p + 2 * (PLANE / 4));
        vf4 a3 = __builtin_nontemporal_load(p + 3 * (PLANE / 4));
        vf4 a4 = __builtin_nontemporal_load(p + 4 * (PLANE / 4));
        vf4 a5 = __builtin_nontemporal_load(p + 5 * (PLANE / 4));
        vf4 a6 = __builtin_nontemporal_load(p + 6 * (PLANE / 4));
        vf4 a7 = __builtin_nontemporal_load(p + 7 * (PLANE / 4));
        acc = te[kk] * a0 + acc;
        acc = te[kk + 1] * a1 + acc;
        acc = te[kk + 2] * a2 + acc;
        acc = te[kk + 3] * a3 + acc;
        acc = te[kk + 4] * a4 + acc;
        acc = te[kk + 5] * a5 + acc;
        acc = te[kk + 6] * a6 + acc;
        acc = te[kk + 7] * a7 + acc;
    }
    acc += ((const vf4*)cv)[s4];
    ((vf4*)rs)[s4] = acc;
}

// ---------------------------------------------------------------------------
// K6 (tiled): inverse Legendre. grid (j=127, thalf=2), block 256.
// ---------------------------------------------------------------------------
__global__ __launch_bounds__(256) void k_isht(const float* __restrict__ Pf,
                                              const float* __restrict__ rsr,
                                              const float* __restrict__ rsi,
                                              float* __restrict__ fo_r,
                                              float* __restrict__ fo_i) {
    __shared__ float Pl[LMAX * 32];
    __shared__ float rr[LMAX * CCH], ri[LMAX * CCH];
    int j = blockIdx.x;
    int half = blockIdx.y;
    int tid = threadIdx.x;
    for (int idx = tid; idx < LMAX * 32; idx += 256) {
        int l = idx >> 5, tloc = idx & 31;
        Pl[idx] = Pf[j * 4096 + l * 64 + (half * 32 + tloc)];
    }
    for (int idx = tid; idx < LMAX * CCH; idx += 256) {
        int l = idx >> 6;
        rr[idx] = rsr[l * ROW + j * 64 + (idx & 63)];
        ri[idx] = rsi[l * ROW + j * 64 + (idx & 63)];
    }
    __syncthreads();
    int c = tid & 63, tb = tid >> 6;
    float ar[8] = {}, ai[8] = {};
    for (int l = 0; l < LMAX; ++l) {
        float rv = rr[l * 64 + c], iv = ri[l * 64 + c];
#pragma unroll
        for (int q = 0; q < 8; ++q) {
            float pv = Pl[l * 32 + (tb + 4 * q)];
            ar[q] = fmaf(pv, rv, ar[q]);
            ai[q] = fmaf(pv, iv, ai[q]);
        }
    }
#pragma unroll
    for (int q = 0; q < 8; ++q) {
        int t = half * 32 + tb + 4 * q;
        fo_r[t * ROW + j * 64 + c] = ar[q];
        fo_i[t * ROW + j * 64 + c] = ai[q];
    }
}

// ---------------------------------------------------------------------------
// K7 (tiled): inverse DFT + r18's PROVEN +1-shifted bf16 store.
// DO NOT CHANGE THE STORE PATTERN.
// ---------------------------------------------------------------------------
__global__ __launch_bounds__(256) void k_idft(const float* __restrict__ fo_r,
                                              const float* __restrict__ fo_i,
                                              __hip_bfloat16* __restrict__ out) {
    __shared__ float fr[NLON * CCH], fi[NLON * CCH];
    __shared__ float ctab[NLON], stab[NLON];
    int t = blockIdx.x;
    int nbase = blockIdx.y * 32;
    int tid = threadIdx.x;
    for (int idx = tid; idx < NLON * CCH; idx += 256) {
        fr[idx] = fo_r[t * ROW + idx];
        fi[idx] = fo_i[t * ROW + idx];
    }
    if (tid < NLON) {
        double th = 2.0 * PI_D * (double)tid / 127.0;
        ctab[tid] = (float)cos(th);
        stab[tid] = (float)sin(th);
    }
    __syncthreads();
    int nl = tid & 31, cg = tid >> 5;
    int n = nbase + nl;
    bool act = (n < NLON);
    int step = act ? n : 0;
    int p = act ? (64 * n) % 127 : 0;
    float ar[8] = {}, ai[8] = {};
    for (int jj = 0; jj < NLON; ++jj) {
        float cv = ctab[p], sv = stab[p];
#pragma unroll
        for (int q = 0; q < 8; ++q) {
            float frv = fr[jj * 64 + cg + 8 * q];
            float fiv = fi[jj * 64 + cg + 8 * q];
            ar[q] = fmaf(frv, cv, fmaf(-fiv, sv, ar[q]));
            ai[q] = fmaf(frv, sv, fmaf(fiv, cv, ai[q]));
        }
        p += step; if (p >= 127) p -= 127;
    }
    if (act) {
#pragma unroll
        for (int q = 0; q < 8; ++q) {
            int cc = cg + 8 * q;
            size_t pp = ((size_t)cc * 64 + t) * 127 + n;
            out[2 * pp + 1] = __float2bfloat16(ar[q]);
            if (pp + 1 < (size_t)PLANE)
                out[2 * pp + 2] = __float2bfloat16(ai[q]);
            if (pp == 0)
                out[0] = __float2bfloat16(0.0f);
        }
    }
}

// ---------------------------------------------------------------------------
static inline bool rng_overlap(uintptr_t a0, uintptr_t a1, uintptr_t b0, uintptr_t b1) {
    return (a0 < b1) && (b0 < a1);
}

extern "C" void kernel_launch(void* const* d_in, const int* in_sizes, int n_in,
                              void* d_out, int out_size, void* d_ws, size_t ws_size,
                              hipStream_t stream) {
    const float* x    = (const float*)d_in[0];
    const float* temb = (const float*)d_in[1];
    const float* Wr   = (const float*)d_in[2];
    const float* Wi   = (const float*)d_in[3];
    const float* dwr  = (const float*)d_in[4];
    const float* dwi  = (const float*)d_in[5];

    __hip_bfloat16* out = (__hip_bfloat16*)d_out;
    dim3 g2(127, 64);

    // ---- host-side environment guard (established clean in r10) ----
    if (d_ws == nullptr || ws_size < NEEDED_WS) {
        size_t mb = ws_size >> 20;
        if (mb > 60) mb = 60;
        k_band<<<g2, 64, 0, stream>>>(20000.0f + 256.0f * (float)mb, out);
        return;
    }
    int bits = 0;
    {
        bool ok = (n_in >= 6) && (in_sizes[0] == 520192) && (in_sizes[1] == 128) &&
                  (in_sizes[2] == 262144) && (in_sizes[3] == 262144) &&
                  (in_sizes[4] == 66584576) && (in_sizes[5] == 66584576);
        if (!ok) bits |= 1;
    }
    uintptr_t w0 = (uintptr_t)d_ws, w1 = w0 + NEEDED_WS;
    uintptr_t o0 = (uintptr_t)d_out, o1 = o0 + (size_t)out_size * 2;
    if (rng_overlap(w0, w1, o0, o1)) bits |= 4;
    for (int i = 0; i < n_in && i < 6; ++i) {
        uintptr_t b0 = (uintptr_t)d_in[i];
        uintptr_t b1 = b0 + (size_t)in_sizes[i] * 4;
        if (rng_overlap(w0, w1, b0, b1)) bits |= 8;
    }
    if (bits) {
        k_band<<<g2, 64, 0, stream>>>(3000.0f + 400.0f * (float)bits, out);
        return;
    }

    // ---- optimized pipeline (values identical; r18 output layout) ----
    char* ws = (char*)d_ws;
    double* xg = (double*)ws;                 // 512
    float* wgf = (float*)(ws + 512);          // 256
    size_t off = 1024;
    float* Pf = (float*)(ws + off); off += (size_t)PLANE * 4;
    float* Ar = (float*)(ws + off); off += (size_t)PLANE * 4;
    float* Ai = (float*)(ws + off); off += (size_t)PLANE * 4;
    float* Br = (float*)(ws + off); off += (size_t)PLANE * 4;
    float* Bi = (float*)(ws + off);

    k_gauss   <<<1, 64, 0, stream>>>(xg, wgf);
    k_legendre<<<64, 64, 0, stream>>>(xg, Pf);
    k_dft_fwd <<<dim3(64, 4), 256, 0, stream>>>(x, Ar, Ai);
    k_sht     <<<dim3(127, 2), 256, 0, stream>>>(Pf, wgf, Ar, Ai, Br, Bi);
    k_conv    <<<dim3(64, 4), 256, 0, stream>>>(Br, Bi, Wr, Wi, Ar, Ai);
    k_dense1  <<<PLANE / 1024, 256, 0, stream>>>(temb, dwr, Ar, Br);  // real
    k_dense1  <<<PLANE / 1024, 256, 0, stream>>>(temb, dwi, Ai, Bi);  // imag
    k_isht    <<<dim3(127, 2), 256, 0, stream>>>(Pf, Br, Bi, Ar, Ai);
    k_idft    <<<dim3(64, 4), 256, 0, stream>>>(Ar, Ai, out);
}